// Round 3
// baseline (2389.699 us; speedup 1.0000x reference)
//
#include <hip/hip_runtime.h>

#define USER_NUM 100000
#define ITEM_NUM 50000
#define NTOT     (USER_NUM + ITEM_NUM)
#define EMB      64
#define GAMMA    0.5f
#define NLAYERS  3
#define EPS      1e-12f

#define SCAN_CHUNK 256
#define NCHUNKS    ((NTOT + SCAN_CHUNK - 1) / SCAN_CHUNK)   // 586

#define BIN_SHIFT  6
#define BIN_ROWS   (1 << BIN_SHIFT)                          // 64 rows / bin
#define NBINS      ((NTOT + BIN_ROWS - 1) >> BIN_SHIFT)      // 2344
#define COL_MASK   ((1u << (32 - BIN_SHIFT)) - 1u)           // low 26 bits

// ===========================================================================
// Shared kernels
// ===========================================================================

// init: X = normalize(concat(user,item)), out = GAMMA * concat(user,item).
__global__ void init_kernel(const float* __restrict__ user_emb,
                            const float* __restrict__ item_emb,
                            float* __restrict__ X,
                            float* __restrict__ out) {
    int tid = blockIdx.x * blockDim.x + threadIdx.x;
    int row = tid >> 4;
    if (row >= NTOT) return;
    int l = tid & 15;
    const float* src = (row < USER_NUM)
        ? user_emb + (size_t)row * EMB
        : item_emb + (size_t)(row - USER_NUM) * EMB;
    float4 v = reinterpret_cast<const float4*>(src)[l];
    float4 o = v; o.x *= GAMMA; o.y *= GAMMA; o.z *= GAMMA; o.w *= GAMMA;
    reinterpret_cast<float4*>(out)[(size_t)row * 16 + l] = o;
    float ss = v.x * v.x + v.y * v.y + v.z * v.z + v.w * v.w;
    ss += __shfl_xor(ss, 1);
    ss += __shfl_xor(ss, 2);
    ss += __shfl_xor(ss, 4);
    ss += __shfl_xor(ss, 8);
    float inv = 1.0f / (sqrtf(ss) + EPS);
    v.x *= inv; v.y *= inv; v.z *= inv; v.w *= inv;
    reinterpret_cast<float4*>(X)[(size_t)row * 16 + l] = v;
}

// histogram with int4-vectorized index reads: counts[r]++ over all nnz
__global__ void hist4_kernel(const int* __restrict__ rows,
                             int* __restrict__ counts, int nnz) {
    int tid = blockIdx.x * blockDim.x + threadIdx.x;
    int stride = gridDim.x * blockDim.x;
    int nnz4 = nnz >> 2;
    for (int i = tid; i < nnz4; i += stride) {
        int4 r4 = reinterpret_cast<const int4*>(rows)[i];
        atomicAdd(&counts[r4.x], 1);
        atomicAdd(&counts[r4.y], 1);
        atomicAdd(&counts[r4.z], 1);
        atomicAdd(&counts[r4.w], 1);
    }
    if (tid == 0)
        for (int i = nnz4 << 2; i < nnz; ++i) atomicAdd(&counts[rows[i]], 1);
}

// scan step A: per-chunk sums
__global__ void scan_sums_kernel(const int* __restrict__ counts,
                                 int* __restrict__ chunk_sums) {
    __shared__ int sdata[SCAN_CHUNK];
    int idx = blockIdx.x * SCAN_CHUNK + threadIdx.x;
    int v = (idx < NTOT) ? counts[idx] : 0;
    sdata[threadIdx.x] = v;
    __syncthreads();
    for (int off = SCAN_CHUNK / 2; off > 0; off >>= 1) {
        if (threadIdx.x < off) sdata[threadIdx.x] += sdata[threadIdx.x + off];
        __syncthreads();
    }
    if (threadIdx.x == 0) chunk_sums[blockIdx.x] = sdata[0];
}

// scan step B: serial exclusive scan of chunk sums
__global__ void scan_offsets_kernel(int* __restrict__ chunk_sums,
                                    int* __restrict__ row_ptr) {
    if (threadIdx.x == 0 && blockIdx.x == 0) {
        int running = 0;
        for (int b = 0; b < NCHUNKS; ++b) {
            int t = chunk_sums[b];
            chunk_sums[b] = running;
            running += t;
        }
        row_ptr[NTOT] = running;
    }
}

// scan step C: intra-chunk exclusive scan + chunk offset -> row_ptr & cursor
__global__ void scan_write_kernel(const int* __restrict__ counts,
                                  const int* __restrict__ chunk_sums,
                                  int* __restrict__ row_ptr,
                                  int* __restrict__ cursor) {
    __shared__ int temp[SCAN_CHUNK];
    int idx = blockIdx.x * SCAN_CHUNK + threadIdx.x;
    int v = (idx < NTOT) ? counts[idx] : 0;
    temp[threadIdx.x] = v;
    __syncthreads();
    for (int off = 1; off < SCAN_CHUNK; off <<= 1) {
        int t = (threadIdx.x >= off) ? temp[threadIdx.x - off] : 0;
        __syncthreads();
        temp[threadIdx.x] += t;
        __syncthreads();
    }
    if (idx < NTOT) {
        int excl = temp[threadIdx.x] - v + chunk_sums[blockIdx.x];
        row_ptr[idx] = excl;
        cursor[idx]  = excl;
    }
}

// ===========================================================================
// Binned two-pass CSR build (fast path)
// ===========================================================================

// bin cursor init: binc[b] = row_ptr[b * BIN_ROWS]
__global__ void binc_init_kernel(const int* __restrict__ row_ptr,
                                 int* __restrict__ binc) {
    int b = blockIdx.x * blockDim.x + threadIdx.x;
    if (b < NBINS) binc[b] = row_ptr[b << BIN_SHIFT];
}

// pass 1: scatter packed {r_low|c, val} records into bin-contiguous staging.
// Consecutive positions within a bin => write-combining friendly.
__global__ void binscat_kernel(const int* __restrict__ rows,
                               const int* __restrict__ cols,
                               const float* __restrict__ vals,
                               int* __restrict__ binc,
                               int2* __restrict__ staging, int nnz) {
    int tid = blockIdx.x * blockDim.x + threadIdx.x;
    int stride = gridDim.x * blockDim.x;
    int nnz4 = nnz >> 2;
    for (int i = tid; i < nnz4; i += stride) {
        int4   r4 = reinterpret_cast<const int4*>(rows)[i];
        int4   c4 = reinterpret_cast<const int4*>(cols)[i];
        float4 v4 = reinterpret_cast<const float4*>(vals)[i];
        {
            int pos = atomicAdd(&binc[r4.x >> BIN_SHIFT], 1);
            staging[pos] = make_int2(((r4.x & (BIN_ROWS - 1)) << (32 - BIN_SHIFT)) | c4.x,
                                     __float_as_int(v4.x));
        }
        {
            int pos = atomicAdd(&binc[r4.y >> BIN_SHIFT], 1);
            staging[pos] = make_int2(((r4.y & (BIN_ROWS - 1)) << (32 - BIN_SHIFT)) | c4.y,
                                     __float_as_int(v4.y));
        }
        {
            int pos = atomicAdd(&binc[r4.z >> BIN_SHIFT], 1);
            staging[pos] = make_int2(((r4.z & (BIN_ROWS - 1)) << (32 - BIN_SHIFT)) | c4.z,
                                     __float_as_int(v4.z));
        }
        {
            int pos = atomicAdd(&binc[r4.w >> BIN_SHIFT], 1);
            staging[pos] = make_int2(((r4.w & (BIN_ROWS - 1)) << (32 - BIN_SHIFT)) | c4.w,
                                     __float_as_int(v4.w));
        }
    }
    if (tid == 0) {
        for (int i = nnz4 << 2; i < nnz; ++i) {
            int r = rows[i];
            int pos = atomicAdd(&binc[r >> BIN_SHIFT], 1);
            staging[pos] = make_int2(((r & (BIN_ROWS - 1)) << (32 - BIN_SHIFT)) | cols[i],
                                     __float_as_int(vals[i]));
        }
    }
}

// pass 2: one block per bin; sequential read of bin records, row-cursor
// scatter into the bin's own ~27 KB cv window (L2-local, no amplification).
__global__ void binfix_kernel(const int2* __restrict__ staging,
                              const int* __restrict__ row_ptr,
                              int* __restrict__ cursor,
                              int2* __restrict__ cv) {
    int b = blockIdx.x;
    int rbase = b << BIN_SHIFT;
    int rend  = rbase + BIN_ROWS; if (rend > NTOT) rend = NTOT;
    int bs = row_ptr[rbase];
    int be = row_ptr[rend];
    for (int j = bs + threadIdx.x; j < be; j += blockDim.x) {
        int2 rec = staging[j];
        int r = rbase + (int)((unsigned)rec.x >> (32 - BIN_SHIFT));
        int c = rec.x & (int)COL_MASK;
        int pos = atomicAdd(&cursor[r], 1);
        cv[pos] = make_int2(c, rec.y);
    }
}

// legacy single-pass build (fallback path)
__global__ void build_kernel(const int* __restrict__ rows,
                             const int* __restrict__ cols,
                             const float* __restrict__ vals,
                             int* __restrict__ cursor,
                             int2* __restrict__ cv, int nnz) {
    int stride = gridDim.x * blockDim.x;
    for (int i = blockIdx.x * blockDim.x + threadIdx.x; i < nnz; i += stride) {
        int r = rows[i];
        int pos = atomicAdd(&cursor[r], 1);
        cv[pos] = make_int2(cols[i], __float_as_int(vals[i]));
    }
}

// ===========================================================================
// Gather SpMM (shared by both CSR paths)
// ===========================================================================
template <int WRITE_NORM>
__global__ void spmm_csr_kernel(const int* __restrict__ row_ptr,
                                const int2* __restrict__ cv,
                                const float* __restrict__ X,
                                float* __restrict__ Y,
                                float* __restrict__ out,
                                float scale) {
    int wave = (blockIdx.x * blockDim.x + threadIdx.x) >> 6;
    if (wave >= NTOT) return;
    int lane = threadIdx.x & 63;
    int start = row_ptr[wave];
    int end   = row_ptr[wave + 1];
    float acc = 0.0f;
#pragma unroll 4
    for (int j = start; j < end; ++j) {
        int2 cvj = cv[j];
        float v  = __int_as_float(cvj.y);
        acc += v * X[(size_t)cvj.x * EMB + lane];
    }
    size_t o = (size_t)wave * EMB + lane;
    out[o] += scale * acc;
    if (WRITE_NORM) {
        float ss = acc * acc;
        ss += __shfl_xor(ss, 1);
        ss += __shfl_xor(ss, 2);
        ss += __shfl_xor(ss, 4);
        ss += __shfl_xor(ss, 8);
        ss += __shfl_xor(ss, 16);
        ss += __shfl_xor(ss, 32);
        float inv = 1.0f / (sqrtf(ss) + EPS);
        Y[o] = acc * inv;
    }
}

// ===========================================================================
// Last-resort scatter path (round-1 proven kernels)
// ===========================================================================

__global__ void scale_copy_kernel(const float* __restrict__ src,
                                  float* __restrict__ dst, float a, int n4) {
    int stride = gridDim.x * blockDim.x;
    for (int i = blockIdx.x * blockDim.x + threadIdx.x; i < n4; i += stride) {
        float4 v = reinterpret_cast<const float4*>(src)[i];
        v.x *= a; v.y *= a; v.z *= a; v.w *= a;
        reinterpret_cast<float4*>(dst)[i] = v;
    }
}

__global__ void normalize_kernel(const float* __restrict__ src,
                                 float* __restrict__ dst, int nrows) {
    int tid = blockIdx.x * blockDim.x + threadIdx.x;
    int row = tid >> 4;
    if (row >= nrows) return;
    int l = tid & 15;
    float4 v = reinterpret_cast<const float4*>(src)[(size_t)row * 16 + l];
    float ss = v.x * v.x + v.y * v.y + v.z * v.z + v.w * v.w;
    ss += __shfl_xor(ss, 1);
    ss += __shfl_xor(ss, 2);
    ss += __shfl_xor(ss, 4);
    ss += __shfl_xor(ss, 8);
    float inv = 1.0f / (sqrtf(ss) + EPS);
    v.x *= inv; v.y *= inv; v.z *= inv; v.w *= inv;
    reinterpret_cast<float4*>(dst)[(size_t)row * 16 + l] = v;
}

__global__ void spmm_scatter_kernel(const int* __restrict__ rows,
                                    const int* __restrict__ cols,
                                    const float* __restrict__ vals,
                                    const float* __restrict__ x,
                                    float* __restrict__ y, int nnz) {
    int lane = threadIdx.x & 63;
    int wave = (blockIdx.x * blockDim.x + threadIdx.x) >> 6;
    int nw   = (gridDim.x * blockDim.x) >> 6;
    for (int i = wave; i < nnz; i += nw) {
        int   r = rows[i];
        int   c = cols[i];
        float v = vals[i];
        atomicAdd(&y[(size_t)r * EMB + lane], v * x[(size_t)c * EMB + lane]);
    }
}

__global__ void axpy_kernel(const float* __restrict__ x,
                            float* __restrict__ out, float a, int n4) {
    int stride = gridDim.x * blockDim.x;
    for (int i = blockIdx.x * blockDim.x + threadIdx.x; i < n4; i += stride) {
        float4 v = reinterpret_cast<const float4*>(x)[i];
        float4 o = reinterpret_cast<float4*>(out)[i];
        o.x += a * v.x; o.y += a * v.y; o.z += a * v.z; o.w += a * v.w;
        reinterpret_cast<float4*>(out)[i] = o;
    }
}

// ===========================================================================

extern "C" void kernel_launch(void* const* d_in, const int* in_sizes, int n_in,
                              void* d_out, int out_size, void* d_ws, size_t ws_size,
                              hipStream_t stream) {
    const float* user_emb = (const float*)d_in[0];
    const float* item_emb = (const float*)d_in[1];
    const int*   rows     = (const int*)d_in[2];
    const int*   cols     = (const int*)d_in[3];
    const float* vals     = (const float*)d_in[4];
    const int    nnz      = in_sizes[2];

    float* out = (float*)d_out;
    const int TOTAL = NTOT * EMB;                  // 9,600,000 floats
    const float layer_scale = (1.0f - GAMMA) / NLAYERS;
    const int SPMM_BLOCKS = (NTOT * 64 + 255) / 256;

    // ---- binned fast path layout ----
    // X | cv | row_ptr | cursor | chunks | binc | R(staging; Y aliased at base)
    size_t need_fast = (size_t)TOTAL * 4               // X
                     + (size_t)nnz * 8                 // cv
                     + (size_t)(NTOT + 1) * 4          // row_ptr
                     + (size_t)NTOT * 4                // cursor
                     + (size_t)NCHUNKS * 4             // chunks
                     + (size_t)NBINS * 4               // binc
                     + (size_t)nnz * 8                 // staging (>= Y)
                     + 4096;

    // ---- round-2 CSR path layout ----
    size_t need_csr = (size_t)TOTAL * 4 * 2 + (size_t)nnz * 8
                    + (size_t)(NTOT + 1) * 4 + (size_t)NTOT * 4
                    + (size_t)NCHUNKS * 4 + 1024;

    if (ws_size >= need_fast) {
        char* p = (char*)d_ws;
        float* X       = (float*)p;  p += (size_t)TOTAL * 4;
        int2*  cv      = (int2*)p;   p += (size_t)nnz * 8;
        int*   row_ptr = (int*)p;    p += (size_t)(NTOT + 1) * 4;
        int*   cursor  = (int*)p;    p += (size_t)NTOT * 4;
        int*   chunks  = (int*)p;    p += (size_t)NCHUNKS * 4;
        int*   binc    = (int*)p;    p += (size_t)NBINS * 4;
        p = (char*)(((uintptr_t)p + 15) & ~(uintptr_t)15);
        int2*  staging = (int2*)p;                  // nnz * 8 bytes
        float* Y       = (float*)p;                 // aliased: used after build

        init_kernel<<<(NTOT * 16 + 255) / 256, 256, 0, stream>>>(
            user_emb, item_emb, X, out);

        hipMemsetAsync(cursor, 0, (size_t)NTOT * 4, stream);   // counts
        hist4_kernel<<<2048, 256, 0, stream>>>(rows, cursor, nnz);
        scan_sums_kernel<<<NCHUNKS, SCAN_CHUNK, 0, stream>>>(cursor, chunks);
        scan_offsets_kernel<<<1, 64, 0, stream>>>(chunks, row_ptr);
        scan_write_kernel<<<NCHUNKS, SCAN_CHUNK, 0, stream>>>(cursor, chunks,
                                                              row_ptr, cursor);
        binc_init_kernel<<<(NBINS + 255) / 256, 256, 0, stream>>>(row_ptr, binc);
        binscat_kernel<<<2048, 256, 0, stream>>>(rows, cols, vals, binc,
                                                 staging, nnz);
        binfix_kernel<<<NBINS, 256, 0, stream>>>(staging, row_ptr, cursor, cv);

        spmm_csr_kernel<1><<<SPMM_BLOCKS, 256, 0, stream>>>(
            row_ptr, cv, X, Y, out, layer_scale);
        spmm_csr_kernel<1><<<SPMM_BLOCKS, 256, 0, stream>>>(
            row_ptr, cv, Y, X, out, layer_scale);
        spmm_csr_kernel<0><<<SPMM_BLOCKS, 256, 0, stream>>>(
            row_ptr, cv, X, Y, out, layer_scale);
        return;
    }

    if (ws_size >= need_csr) {
        char* p = (char*)d_ws;
        float* X       = (float*)p;  p += (size_t)TOTAL * 4;
        float* Y       = (float*)p;  p += (size_t)TOTAL * 4;
        int2*  cv      = (int2*)p;   p += (size_t)nnz * 8;
        int*   row_ptr = (int*)p;    p += (size_t)(NTOT + 1) * 4;
        int*   cursor  = (int*)p;    p += (size_t)NTOT * 4;
        int*   chunks  = (int*)p;

        init_kernel<<<(NTOT * 16 + 255) / 256, 256, 0, stream>>>(
            user_emb, item_emb, X, out);
        hipMemsetAsync(cursor, 0, (size_t)NTOT * 4, stream);
        hist4_kernel<<<2048, 256, 0, stream>>>(rows, cursor, nnz);
        scan_sums_kernel<<<NCHUNKS, SCAN_CHUNK, 0, stream>>>(cursor, chunks);
        scan_offsets_kernel<<<1, 64, 0, stream>>>(chunks, row_ptr);
        scan_write_kernel<<<NCHUNKS, SCAN_CHUNK, 0, stream>>>(cursor, chunks,
                                                              row_ptr, cursor);
        build_kernel<<<(nnz + 255) / 256, 256, 0, stream>>>(rows, cols, vals,
                                                            cursor, cv, nnz);

        spmm_csr_kernel<1><<<SPMM_BLOCKS, 256, 0, stream>>>(
            row_ptr, cv, X, Y, out, layer_scale);
        spmm_csr_kernel<1><<<SPMM_BLOCKS, 256, 0, stream>>>(
            row_ptr, cv, Y, X, out, layer_scale);
        spmm_csr_kernel<0><<<SPMM_BLOCKS, 256, 0, stream>>>(
            row_ptr, cv, X, Y, out, layer_scale);
        return;
    }

    // ---- last resort: round-1 scatter path ----
    float* A = (float*)d_ws;
    float* B = A + (size_t)TOTAL;
    const int T4 = TOTAL / 4;

    scale_copy_kernel<<<2048, 256, 0, stream>>>(user_emb, out, GAMMA,
                                                USER_NUM * EMB / 4);
    scale_copy_kernel<<<2048, 256, 0, stream>>>(item_emb, out + (size_t)USER_NUM * EMB,
                                                GAMMA, ITEM_NUM * EMB / 4);
    normalize_kernel<<<(USER_NUM * 16 + 255) / 256, 256, 0, stream>>>(
        user_emb, A, USER_NUM);
    normalize_kernel<<<(ITEM_NUM * 16 + 255) / 256, 256, 0, stream>>>(
        item_emb, A + (size_t)USER_NUM * EMB, ITEM_NUM);

    for (int layer = 0; layer < NLAYERS; ++layer) {
        if (layer > 0)
            normalize_kernel<<<(NTOT * 16 + 255) / 256, 256, 0, stream>>>(B, A, NTOT);
        hipMemsetAsync(B, 0, (size_t)TOTAL * sizeof(float), stream);
        spmm_scatter_kernel<<<8192, 256, 0, stream>>>(rows, cols, vals, A, B, nnz);
        axpy_kernel<<<2048, 256, 0, stream>>>(B, out, layer_scale, T4);
    }
}

// Round 4
// 1622.565 us; speedup vs baseline: 1.4728x; 1.4728x over previous
//
#include <hip/hip_runtime.h>

#define USER_NUM 100000
#define ITEM_NUM 50000
#define NTOT     (USER_NUM + ITEM_NUM)
#define EMB      64
#define GAMMA    0.5f
#define NLAYERS  3
#define EPS      1e-12f

#define SCAN_CHUNK 256
#define NCHUNKS    ((NTOT + SCAN_CHUNK - 1) / SCAN_CHUNK)   // 586

// ---- bf16 helpers (explicit RNE, bit-level) ----
__device__ __forceinline__ unsigned short f2bf(float f) {
    unsigned u = __float_as_uint(f);
    u = (u + 0x7FFFu + ((u >> 16) & 1u)) >> 16;   // round-to-nearest-even
    return (unsigned short)u;
}
__device__ __forceinline__ float bf2f(unsigned short h) {
    return __uint_as_float((unsigned)h << 16);
}

// ===========================================================================
// init: Xh = bf16(normalize(concat(user,item))), out = GAMMA * concat(...)
// 16 lanes per row, 4 dims per lane.
// ===========================================================================
__global__ void init_kernel(const float* __restrict__ user_emb,
                            const float* __restrict__ item_emb,
                            unsigned short* __restrict__ Xh,
                            float* __restrict__ out) {
    int tid = blockIdx.x * blockDim.x + threadIdx.x;
    int row = tid >> 4;
    if (row >= NTOT) return;
    int l = tid & 15;
    const float* src = (row < USER_NUM)
        ? user_emb + (size_t)row * EMB
        : item_emb + (size_t)(row - USER_NUM) * EMB;
    float4 v = reinterpret_cast<const float4*>(src)[l];
    float4 o = v; o.x *= GAMMA; o.y *= GAMMA; o.z *= GAMMA; o.w *= GAMMA;
    reinterpret_cast<float4*>(out)[(size_t)row * 16 + l] = o;
    float ss = v.x * v.x + v.y * v.y + v.z * v.z + v.w * v.w;
    ss += __shfl_xor(ss, 1);
    ss += __shfl_xor(ss, 2);
    ss += __shfl_xor(ss, 4);
    ss += __shfl_xor(ss, 8);
    float inv = 1.0f / (sqrtf(ss) + EPS);
    ushort4 h;
    h.x = f2bf(v.x * inv); h.y = f2bf(v.y * inv);
    h.z = f2bf(v.z * inv); h.w = f2bf(v.w * inv);
    reinterpret_cast<ushort4*>(Xh)[(size_t)row * 16 + l] = h;
}

// ===========================================================================
// histogram (int4-vectorized index reads)
// ===========================================================================
__global__ void hist4_kernel(const int* __restrict__ rows,
                             int* __restrict__ counts, int nnz) {
    int tid = blockIdx.x * blockDim.x + threadIdx.x;
    int stride = gridDim.x * blockDim.x;
    int nnz4 = nnz >> 2;
    for (int i = tid; i < nnz4; i += stride) {
        int4 r4 = reinterpret_cast<const int4*>(rows)[i];
        atomicAdd(&counts[r4.x], 1);
        atomicAdd(&counts[r4.y], 1);
        atomicAdd(&counts[r4.z], 1);
        atomicAdd(&counts[r4.w], 1);
    }
    if (tid == 0)
        for (int i = nnz4 << 2; i < nnz; ++i) atomicAdd(&counts[rows[i]], 1);
}

// ===========================================================================
// 3-step exclusive scan of per-row counts -> row_ptr (and cursor copy)
// ===========================================================================
__global__ void scan_sums_kernel(const int* __restrict__ counts,
                                 int* __restrict__ chunk_sums) {
    __shared__ int sdata[SCAN_CHUNK];
    int idx = blockIdx.x * SCAN_CHUNK + threadIdx.x;
    int v = (idx < NTOT) ? counts[idx] : 0;
    sdata[threadIdx.x] = v;
    __syncthreads();
    for (int off = SCAN_CHUNK / 2; off > 0; off >>= 1) {
        if (threadIdx.x < off) sdata[threadIdx.x] += sdata[threadIdx.x + off];
        __syncthreads();
    }
    if (threadIdx.x == 0) chunk_sums[blockIdx.x] = sdata[0];
}

__global__ void scan_offsets_kernel(int* __restrict__ chunk_sums,
                                    int* __restrict__ row_ptr) {
    if (threadIdx.x == 0 && blockIdx.x == 0) {
        int running = 0;
        for (int b = 0; b < NCHUNKS; ++b) {
            int t = chunk_sums[b];
            chunk_sums[b] = running;
            running += t;
        }
        row_ptr[NTOT] = running;
    }
}

__global__ void scan_write_kernel(const int* __restrict__ counts,
                                  const int* __restrict__ chunk_sums,
                                  int* __restrict__ row_ptr,
                                  int* __restrict__ cursor) {
    __shared__ int temp[SCAN_CHUNK];
    int idx = blockIdx.x * SCAN_CHUNK + threadIdx.x;
    int v = (idx < NTOT) ? counts[idx] : 0;
    temp[threadIdx.x] = v;
    __syncthreads();
    for (int off = 1; off < SCAN_CHUNK; off <<= 1) {
        int t = (threadIdx.x >= off) ? temp[threadIdx.x - off] : 0;
        __syncthreads();
        temp[threadIdx.x] += t;
        __syncthreads();
    }
    if (idx < NTOT) {
        int excl = temp[threadIdx.x] - v + chunk_sums[blockIdx.x];
        row_ptr[idx] = excl;
        cursor[idx]  = excl;
    }
}

// ===========================================================================
// single-pass CSR build (proven round-2 form; int4-vectorized reads).
// Random 8B writes; write-line-amplification-bound but better than any
// sequential-cursor variant (cross-CU line contention — round-3 lesson).
// ===========================================================================
__global__ void build_kernel(const int* __restrict__ rows,
                             const int* __restrict__ cols,
                             const float* __restrict__ vals,
                             int* __restrict__ cursor,
                             int2* __restrict__ cv, int nnz) {
    int tid = blockIdx.x * blockDim.x + threadIdx.x;
    int stride = gridDim.x * blockDim.x;
    int nnz4 = nnz >> 2;
    for (int i = tid; i < nnz4; i += stride) {
        int4   r4 = reinterpret_cast<const int4*>(rows)[i];
        int4   c4 = reinterpret_cast<const int4*>(cols)[i];
        float4 v4 = reinterpret_cast<const float4*>(vals)[i];
        int p0 = atomicAdd(&cursor[r4.x], 1);
        cv[p0] = make_int2(c4.x, __float_as_int(v4.x));
        int p1 = atomicAdd(&cursor[r4.y], 1);
        cv[p1] = make_int2(c4.y, __float_as_int(v4.y));
        int p2 = atomicAdd(&cursor[r4.z], 1);
        cv[p2] = make_int2(c4.z, __float_as_int(v4.z));
        int p3 = atomicAdd(&cursor[r4.w], 1);
        cv[p3] = make_int2(c4.w, __float_as_int(v4.w));
    }
    if (tid == 0) {
        for (int i = nnz4 << 2; i < nnz; ++i) {
            int pos = atomicAdd(&cursor[rows[i]], 1);
            cv[pos] = make_int2(cols[i], __float_as_int(vals[i]));
        }
    }
}

// ===========================================================================
// gather SpMM over bf16 X: one wave per row, lane = dim.
//   acc = sum_j val_j * bf2f(Xh[col_j][lane])
//   out[r] += scale * acc
//   if WRITE_NORM: Yh[r] = bf16(acc / (||acc|| + EPS))
// ===========================================================================
template <int WRITE_NORM>
__global__ void spmm_csr_kernel(const int* __restrict__ row_ptr,
                                const int2* __restrict__ cv,
                                const unsigned short* __restrict__ Xh,
                                unsigned short* __restrict__ Yh,
                                float* __restrict__ out,
                                float scale) {
    int wave = (blockIdx.x * blockDim.x + threadIdx.x) >> 6;
    if (wave >= NTOT) return;
    int lane = threadIdx.x & 63;
    int start = row_ptr[wave];
    int end   = row_ptr[wave + 1];
    float acc = 0.0f;
#pragma unroll 4
    for (int j = start; j < end; ++j) {
        int2 cvj = cv[j];
        float v  = __int_as_float(cvj.y);
        acc += v * bf2f(Xh[(size_t)cvj.x * EMB + lane]);
    }
    size_t o = (size_t)wave * EMB + lane;
    out[o] += scale * acc;
    if (WRITE_NORM) {
        float ss = acc * acc;
        ss += __shfl_xor(ss, 1);
        ss += __shfl_xor(ss, 2);
        ss += __shfl_xor(ss, 4);
        ss += __shfl_xor(ss, 8);
        ss += __shfl_xor(ss, 16);
        ss += __shfl_xor(ss, 32);
        float inv = 1.0f / (sqrtf(ss) + EPS);
        Yh[o] = f2bf(acc * inv);
    }
}

// ===========================================================================
// Last-resort scatter path (round-1 proven kernels)
// ===========================================================================

__global__ void scale_copy_kernel(const float* __restrict__ src,
                                  float* __restrict__ dst, float a, int n4) {
    int stride = gridDim.x * blockDim.x;
    for (int i = blockIdx.x * blockDim.x + threadIdx.x; i < n4; i += stride) {
        float4 v = reinterpret_cast<const float4*>(src)[i];
        v.x *= a; v.y *= a; v.z *= a; v.w *= a;
        reinterpret_cast<float4*>(dst)[i] = v;
    }
}

__global__ void normalize_kernel(const float* __restrict__ src,
                                 float* __restrict__ dst, int nrows) {
    int tid = blockIdx.x * blockDim.x + threadIdx.x;
    int row = tid >> 4;
    if (row >= nrows) return;
    int l = tid & 15;
    float4 v = reinterpret_cast<const float4*>(src)[(size_t)row * 16 + l];
    float ss = v.x * v.x + v.y * v.y + v.z * v.z + v.w * v.w;
    ss += __shfl_xor(ss, 1);
    ss += __shfl_xor(ss, 2);
    ss += __shfl_xor(ss, 4);
    ss += __shfl_xor(ss, 8);
    float inv = 1.0f / (sqrtf(ss) + EPS);
    v.x *= inv; v.y *= inv; v.z *= inv; v.w *= inv;
    reinterpret_cast<float4*>(dst)[(size_t)row * 16 + l] = v;
}

__global__ void spmm_scatter_kernel(const int* __restrict__ rows,
                                    const int* __restrict__ cols,
                                    const float* __restrict__ vals,
                                    const float* __restrict__ x,
                                    float* __restrict__ y, int nnz) {
    int lane = threadIdx.x & 63;
    int wave = (blockIdx.x * blockDim.x + threadIdx.x) >> 6;
    int nw   = (gridDim.x * blockDim.x) >> 6;
    for (int i = wave; i < nnz; i += nw) {
        int   r = rows[i];
        int   c = cols[i];
        float v = vals[i];
        atomicAdd(&y[(size_t)r * EMB + lane], v * x[(size_t)c * EMB + lane]);
    }
}

__global__ void axpy_kernel(const float* __restrict__ x,
                            float* __restrict__ out, float a, int n4) {
    int stride = gridDim.x * blockDim.x;
    for (int i = blockIdx.x * blockDim.x + threadIdx.x; i < n4; i += stride) {
        float4 v = reinterpret_cast<const float4*>(x)[i];
        float4 o = reinterpret_cast<float4*>(out)[i];
        o.x += a * v.x; o.y += a * v.y; o.z += a * v.z; o.w += a * v.w;
        reinterpret_cast<float4*>(out)[i] = o;
    }
}

// ===========================================================================

extern "C" void kernel_launch(void* const* d_in, const int* in_sizes, int n_in,
                              void* d_out, int out_size, void* d_ws, size_t ws_size,
                              hipStream_t stream) {
    const float* user_emb = (const float*)d_in[0];
    const float* item_emb = (const float*)d_in[1];
    const int*   rows     = (const int*)d_in[2];
    const int*   cols     = (const int*)d_in[3];
    const float* vals     = (const float*)d_in[4];
    const int    nnz      = in_sizes[2];

    float* out = (float*)d_out;
    const int TOTAL = NTOT * EMB;                  // 9,600,000
    const float layer_scale = (1.0f - GAMMA) / NLAYERS;
    const int SPMM_BLOCKS = (NTOT * 64 + 255) / 256;

    // ---- bf16 CSR path layout: Xh | Yh | cv | row_ptr | cursor | chunks ----
    size_t need = (size_t)TOTAL * 2 * 2            // Xh, Yh (bf16)
                + (size_t)nnz * 8                  // cv
                + (size_t)(NTOT + 1) * 4
                + (size_t)NTOT * 4
                + (size_t)NCHUNKS * 4
                + 1024;

    if (ws_size >= need) {
        char* p = (char*)d_ws;
        unsigned short* Xh = (unsigned short*)p;  p += (size_t)TOTAL * 2;
        unsigned short* Yh = (unsigned short*)p;  p += (size_t)TOTAL * 2;
        int2* cv           = (int2*)p;            p += (size_t)nnz * 8;
        int*  row_ptr      = (int*)p;             p += (size_t)(NTOT + 1) * 4;
        int*  cursor       = (int*)p;             p += (size_t)NTOT * 4;
        int*  chunks       = (int*)p;

        init_kernel<<<(NTOT * 16 + 255) / 256, 256, 0, stream>>>(
            user_emb, item_emb, Xh, out);

        hipMemsetAsync(cursor, 0, (size_t)NTOT * 4, stream);   // counts
        hist4_kernel<<<2048, 256, 0, stream>>>(rows, cursor, nnz);
        scan_sums_kernel<<<NCHUNKS, SCAN_CHUNK, 0, stream>>>(cursor, chunks);
        scan_offsets_kernel<<<1, 64, 0, stream>>>(chunks, row_ptr);
        scan_write_kernel<<<NCHUNKS, SCAN_CHUNK, 0, stream>>>(cursor, chunks,
                                                              row_ptr, cursor);
        build_kernel<<<2048, 256, 0, stream>>>(rows, cols, vals, cursor, cv, nnz);

        spmm_csr_kernel<1><<<SPMM_BLOCKS, 256, 0, stream>>>(
            row_ptr, cv, Xh, Yh, out, layer_scale);
        spmm_csr_kernel<1><<<SPMM_BLOCKS, 256, 0, stream>>>(
            row_ptr, cv, Yh, Xh, out, layer_scale);
        spmm_csr_kernel<0><<<SPMM_BLOCKS, 256, 0, stream>>>(
            row_ptr, cv, Xh, Yh, out, layer_scale);
        return;
    }

    // ---- last resort: round-1 scatter path (needs 76.8 MB) ----
    float* A = (float*)d_ws;
    float* B = A + (size_t)TOTAL;
    const int T4 = TOTAL / 4;

    scale_copy_kernel<<<2048, 256, 0, stream>>>(user_emb, out, GAMMA,
                                                USER_NUM * EMB / 4);
    scale_copy_kernel<<<2048, 256, 0, stream>>>(item_emb, out + (size_t)USER_NUM * EMB,
                                                GAMMA, ITEM_NUM * EMB / 4);
    normalize_kernel<<<(USER_NUM * 16 + 255) / 256, 256, 0, stream>>>(
        user_emb, A, USER_NUM);
    normalize_kernel<<<(ITEM_NUM * 16 + 255) / 256, 256, 0, stream>>>(
        item_emb, A + (size_t)USER_NUM * EMB, ITEM_NUM);

    for (int layer = 0; layer < NLAYERS; ++layer) {
        if (layer > 0)
            normalize_kernel<<<(NTOT * 16 + 255) / 256, 256, 0, stream>>>(B, A, NTOT);
        hipMemsetAsync(B, 0, (size_t)TOTAL * sizeof(float), stream);
        spmm_scatter_kernel<<<8192, 256, 0, stream>>>(rows, cols, vals, A, B, nnz);
        axpy_kernel<<<2048, 256, 0, stream>>>(B, out, layer_scale, T4);
    }
}